// Round 1
// 82.927 us; speedup vs baseline: 1.1814x; 1.1814x over previous
//
#include <hip/hip_runtime.h>
#include <hip/hip_bf16.h>

#define NUM_CLASSES 200
#define NF 128
#define NP 2000
#define NPC 10          // prototypes per class
#define HW 196
#define MPAD 208        // 13 * 16 hw rows (padded)
#define NB 64
#define EPSV 1e-4f
#define TROW 17         // fp32 staging tile row stride (floats)

typedef __attribute__((ext_vector_type(8))) short short8;   // 8 bf16 = 4 VGPR
typedef __attribute__((ext_vector_type(4))) float f32x4;

static __device__ __forceinline__ unsigned short f2bf(float x) {
    __hip_bfloat16 h = __float2bfloat16(x);
    return __builtin_bit_cast(unsigned short, h);
}

// async global->LDS staging, 16B/lane and 4B/lane variants (size must be literal)
static __device__ __forceinline__ void gl_lds16(const void* g, void* l) {
    __builtin_amdgcn_global_load_lds(
        (const __attribute__((address_space(1))) void*)g,
        (__attribute__((address_space(3))) void*)l, 16, 0, 0);
}
static __device__ __forceinline__ void gl_lds4(const void* g, void* l) {
    __builtin_amdgcn_global_load_lds(
        (const __attribute__((address_space(1))) void*)g,
        (__attribute__((address_space(3))) void*)l, 4, 0, 0);
}

// ---- kernel 0: once-per-n transpose/cvt prep ---------------------------------
// grid (64 n, 13 chunks). Each block transposes one 16-hw x 128-k fp32 chunk of
// f[n] into bf16, writes it to G pre-XOR-swizzled in 16B units (unit kg of row
// hw stored at position kg ^ (hw & 15)) so kdist can global_load_lds it
// LINEARLY into LDS and read with the existing swizzled MFMA pattern.
// Also computes exact fp32 xsq per hw row, and zeroes the logits accumulator.
__global__ __launch_bounds__(256) void kprep(const float* __restrict__ f,
                                             uint4* __restrict__ G,
                                             float* __restrict__ xsqG,
                                             float* __restrict__ logits) {
    __shared__ float tile[NF * TROW];   // 8,704 B fp32 staging [k][hw_local]

    const int n   = blockIdx.x;
    const int mt  = blockIdx.y;
    const int t   = threadIdx.x;
    const int hw0 = mt * 16;

    if (mt == 0 && t < NUM_CLASSES) logits[(size_t)n * NUM_CLASSES + t] = 0.f;

    // load phase: k row = t>>2 (and +64), 4 hw values at (t&3)*4
    const int kb  = t >> 2;
    const int hwl = (t & 3) * 4;
    float4 v0 = make_float4(0.f, 0.f, 0.f, 0.f), v1 = v0;
    if (hw0 + hwl + 4 <= HW) {
        v0 = *(const float4*)(f + ((size_t)n * NF + kb) * HW + hw0 + hwl);
        v1 = *(const float4*)(f + ((size_t)n * NF + kb + 64) * HW + hw0 + hwl);
    }
    tile[kb * TROW + hwl + 0] = v0.x;
    tile[kb * TROW + hwl + 1] = v0.y;
    tile[kb * TROW + hwl + 2] = v0.z;
    tile[kb * TROW + hwl + 3] = v0.w;
    tile[(kb + 64) * TROW + hwl + 0] = v1.x;
    tile[(kb + 64) * TROW + hwl + 1] = v1.y;
    tile[(kb + 64) * TROW + hwl + 2] = v1.z;
    tile[(kb + 64) * TROW + hwl + 3] = v1.w;
    __syncthreads();

    // transpose phase: hw row = t>>4, 8-k group = t&15; cvt + exact xsq
    const int hwl2 = t >> 4;
    const int kg   = t & 15;
    float xp = 0.f;
    unsigned short u[8];
    #pragma unroll
    for (int j = 0; j < 8; ++j) {
        float val = tile[(kg * 8 + j) * TROW + hwl2];
        xp += val * val;
        u[j] = f2bf(val);
    }
    // pre-swizzled global store: 1KB contiguous per wave (permuted within rows)
    G[((size_t)n * MPAD + hw0 + hwl2) * 16 + (kg ^ hwl2)] = *(uint4*)u;

    // xsq: butterfly over the 16 consecutive lanes sharing hwl2
    xp += __shfl_xor(xp, 1, 64);
    xp += __shfl_xor(xp, 2, 64);
    xp += __shfl_xor(xp, 4, 64);
    xp += __shfl_xor(xp, 8, 64);
    if (kg == 0) xsqG[(size_t)n * 256 + hw0 + hwl2] = (hw0 + hwl2 < HW) ? xp : 3.0e38f;
}

// ---- kernel 1: distance kernel (MFMA) ----------------------------------------
// grid (64 n, 8 p-tiles of 256) [n fastest -> same-n blocks share an XCD L2].
// B-matrix arrives via 13x global_load_lds (linear dest == pre-swizzled G), ONE
// barrier total. A-frags + exact psq from fp32 protos unchanged. Epilogue:
// running-min reduce, min_out write, sim -> LDS, segmented per-class atomicAdd
// into the logits accumulator (algebraic replacement for the W GEMM).
__global__ __launch_bounds__(256, 2) void kdist(const uint4* __restrict__ G,
                                                const float* __restrict__ xsqG,
                                                const float* __restrict__ protos,
                                                float* __restrict__ min_out,
                                                float* __restrict__ logits) {
    __shared__ unsigned short sf[MPAD * NF];   // 53,248 B bf16 B-matrix (swizzled)
    __shared__ float sxsq[256];
    __shared__ float ssim[256];

    const int n    = blockIdx.x;
    const int pt   = blockIdx.y;
    const int t    = threadIdx.x;
    const int wave = t >> 6;
    const int lane = t & 63;
    const int row  = lane & 15;
    const int quad = lane >> 4;
    const int pb   = pt * 256 + wave * 64;

    // ---- issue B staging first: 13 x (256 lanes x 16B) + xsq, stays in flight
    const uint4* gsrc = G + (size_t)n * (MPAD * 16);
    #pragma unroll
    for (int i = 0; i < 13; ++i)
        gl_lds16(gsrc + i * 256 + t, (char*)sf + ((size_t)i * 256 + wave * 64) * 16);
    gl_lds4(xsqG + (size_t)n * 256 + t, (char*)sxsq + (size_t)wave * 64 * 4);

    // ---- A frags from fp32 protos (cvt bf16) + exact fp32 psq ----------------
    short8 A[4][4];
    float psum[4];
    #pragma unroll
    for (int g = 0; g < 4; ++g) {
        int p = pb + g * 16 + row;
        const float* ap = protos + (size_t)(p < NP ? p : NP - 1) * NF + quad * 8;
        psum[g] = 0.f;
        #pragma unroll
        for (int kk = 0; kk < 4; ++kk) {
            float4 v0 = *(const float4*)(ap + kk * 32);
            float4 v1 = *(const float4*)(ap + kk * 32 + 4);
            psum[g] += v0.x * v0.x + v0.y * v0.y + v0.z * v0.z + v0.w * v0.w
                     + v1.x * v1.x + v1.y * v1.y + v1.z * v1.z + v1.w * v1.w;
            short8 a;
            a[0] = (short)f2bf(v0.x); a[1] = (short)f2bf(v0.y);
            a[2] = (short)f2bf(v0.z); a[3] = (short)f2bf(v0.w);
            a[4] = (short)f2bf(v1.x); a[5] = (short)f2bf(v1.y);
            a[6] = (short)f2bf(v1.z); a[7] = (short)f2bf(v1.w);
            A[g][kk] = a;
        }
        psum[g] += __shfl_xor(psum[g], 16, 64);
        psum[g] += __shfl_xor(psum[g], 32, 64);
    }

    __syncthreads();   // compiler emits vmcnt(0) drain here -> staging complete

    // ---- MFMA loop (unchanged, verified swizzled-read pattern) ---------------
    float runmin[4][4];
    #pragma unroll
    for (int g = 0; g < 4; ++g)
        #pragma unroll
        for (int r = 0; r < 4; ++r) runmin[g][r] = 3.0e38f;

    const short8* sfv = (const short8*)sf;   // 16 units per row
    for (int mt = 0; mt < 13; ++mt) {
        const int base = (mt * 16 + row) * 16;
        short8 b0 = sfv[base + ((quad + 0)  ^ row)];
        short8 b1 = sfv[base + ((quad + 4)  ^ row)];
        short8 b2 = sfv[base + ((quad + 8)  ^ row)];
        short8 b3 = sfv[base + ((quad + 12) ^ row)];
        float xv = sxsq[mt * 16 + row];

        #pragma unroll
        for (int g = 0; g < 4; ++g) {
            f32x4 acc = {0.f, 0.f, 0.f, 0.f};
            acc = __builtin_amdgcn_mfma_f32_16x16x32_bf16(A[g][0], b0, acc, 0, 0, 0);
            acc = __builtin_amdgcn_mfma_f32_16x16x32_bf16(A[g][1], b1, acc, 0, 0, 0);
            acc = __builtin_amdgcn_mfma_f32_16x16x32_bf16(A[g][2], b2, acc, 0, 0, 0);
            acc = __builtin_amdgcn_mfma_f32_16x16x32_bf16(A[g][3], b3, acc, 0, 0, 0);
            #pragma unroll
            for (int r = 0; r < 4; ++r)
                runmin[g][r] = fminf(runmin[g][r], xv - 2.f * acc[r]);
        }
    }

    // ---- min over the 16 D-columns, sim, epilogue ----------------------------
    #pragma unroll
    for (int g = 0; g < 4; ++g) {
        #pragma unroll
        for (int off = 1; off < 16; off <<= 1)
            #pragma unroll
            for (int r = 0; r < 4; ++r)
                runmin[g][r] = fminf(runmin[g][r], __shfl_xor(runmin[g][r], off, 64));
        #pragma unroll
        for (int r = 0; r < 4; ++r) {
            // psq for p = pb + g*16 + quad*4 + r lives at lane 20*quad + r
            float psq_sel = __shfl(psum[g], 20 * quad + r, 64);
            int p = pb + g * 16 + quad * 4 + r;
            if (row == 0) {
                float sim = 0.f;
                if (p < NP) {
                    float m = fmaxf(runmin[g][r] + psq_sel, 0.f);
                    min_out[(size_t)n * NP + p] = m;
                    sim = logf((m + 1.f) / (m + EPSV));
                }
                ssim[wave * 64 + g * 16 + quad * 4 + r] = sim;
            }
        }
    }
    __syncthreads();

    // ---- segmented class sums over this block's 256 protos -------------------
    // class c spans protos [c*10, c*10+10); block spans [pt*256, pt*256+256)
    const int pb0  = pt * 256;
    const int pend = (pb0 + 256 < NP) ? pb0 + 256 : NP;
    const int c0   = pb0 / NPC;
    const int c1   = (pend - 1) / NPC;
    if (t <= c1 - c0) {
        int c  = c0 + t;
        int lo = (c * NPC > pb0) ? c * NPC : pb0;
        int hi = (c * NPC + NPC < pend) ? c * NPC + NPC : pend;
        float s = 0.f;
        for (int p = lo; p < hi; ++p) s += ssim[p - pb0];
        atomicAdd(&logits[(size_t)n * NUM_CLASSES + c], s);
    }
}

// ---- kernel 2: finalize logits -----------------------------------------------
// W[c,p] = a (correct) / b (incorrect) by 10-proto class blocks, so
// logits[n,c] = (a-b)*classsum[n,c] + b*totalsum[n]; totalsum = sum_c classsum.
// One block per n; in-place on the accumulator (all reads before writes).
__global__ __launch_bounds__(256) void kfinal(const float* __restrict__ W,
                                              float* __restrict__ logits) {
    __shared__ float red[4];
    const int n = blockIdx.x;
    const int t = threadIdx.x;
    const float a = W[0];      // correct-class weight   (1.0)
    const float b = W[NPC];    // incorrect-class weight (-0.5)

    float v = (t < NUM_CLASSES) ? logits[(size_t)n * NUM_CLASSES + t] : 0.f;
    float s = v;
    #pragma unroll
    for (int off = 32; off; off >>= 1) s += __shfl_xor(s, off, 64);
    if ((t & 63) == 0) red[t >> 6] = s;
    __syncthreads();
    const float tot = red[0] + red[1] + red[2] + red[3];
    if (t < NUM_CLASSES)
        logits[(size_t)n * NUM_CLASSES + t] = (a - b) * v + b * tot;
}

extern "C" void kernel_launch(void* const* d_in, const int* in_sizes, int n_in,
                              void* d_out, int out_size, void* d_ws, size_t ws_size,
                              hipStream_t stream) {
    const float* f      = (const float*)d_in[0];  // 64x128x14x14
    const float* protos = (const float*)d_in[1];  // 2000x128
    const float* W      = (const float*)d_in[2];  // 200x2000

    float* logits   = (float*)d_out;
    float* min_dist = (float*)d_out + NB * NUM_CLASSES;

    // workspace: G bf16 [64][208][16 units][16B] then xsq [64][256] f32
    uint4* G    = (uint4*)d_ws;
    float* xsqG = (float*)((char*)d_ws + (size_t)NB * MPAD * 16 * sizeof(uint4));

    kprep<<<dim3(NB, 13), 256, 0, stream>>>(f, G, xsqG, logits);
    kdist<<<dim3(NB, 8), 256, 0, stream>>>(G, xsqG, protos, min_dist, logits);
    kfinal<<<NB, 256, 0, stream>>>(W, logits);
}